// Round 11
// baseline (219.584 us; speedup 1.0000x reference)
//
#include <hip/hip_runtime.h>

#define NIN   55296
#define CIN   256
#define COUT  256
#define NTH   512
#define NBLK  432   // 2 parities * 216 tiles of 256 rows

typedef __attribute__((ext_vector_type(8))) _Float16 half8;
typedef __attribute__((ext_vector_type(4))) _Float16 half4;
typedef __attribute__((ext_vector_type(4))) float f32x4;

typedef const __attribute__((address_space(1))) void* gp_t;
typedef __attribute__((address_space(3))) void* lp_t;
__device__ __forceinline__ void gload16(const void* g, char* l) {
  __builtin_amdgcn_global_load_lds((gp_t)g, (lp_t)l, 16, 0, 0);
}

// ---------- pre-pass: features f32 -> f16 ----------
__global__ void k_feat_cvt(const float* __restrict__ f, _Float16* __restrict__ o, int n4) {
  int i = blockIdx.x * blockDim.x + threadIdx.x;
  if (i >= n4) return;
  f32x4 v = ((const f32x4*)f)[i];
  half4 r;
  r[0] = (_Float16)v[0]; r[1] = (_Float16)v[1];
  r[2] = (_Float16)v[2]; r[3] = (_Float16)v[3];
  ((half4*)o)[i] = r;
}

// ---------- pre-pass: W f32 [27][cin][cout] -> f16 transposed Wt [27][cout][cin]
__global__ void k_w_cvt(const float* __restrict__ W, _Float16* __restrict__ Wt,
                        float* __restrict__ zeros) {
  int i = blockIdx.x * blockDim.x + threadIdx.x;
  int d   = i >> 16;
  int rem = i & 65535;
  int n   = rem >> 8;
  int k   = rem & 255;
  Wt[i] = (_Float16)W[(d << 16) + (k << 8) + n];
  if (blockIdx.x == 0 && threadIdx.x < 128) zeros[threadIdx.x] = 0.0f;
}

// ---------- main: 8-wave 256x256 tile, BK=64; r3 body + counted vmcnt ----------
// LDS 160KB exactly: A triple-buffer @ (s%3)*32768 (ks0 16KB + ks1 16KB),
//                    B double-buffer @ 98304 + (s&1)*32768 (ks0 + ks1).
// Per step s: s_waitcnt vmcnt(4) (B(s) landed => A(s),A(s+1) retired in-order;
//   A(s+2)'s 4 loads stay in flight) -> s_barrier -> issue B(s+1) THEN A(s+2)
//   -> 24 ds_reads -> 2 x 32 MFMA (compiler's counted lgkm drains reads under MFMA).
// A loads get TWO steps of flight (~4000 cyc) to absorb HBM gather misses (~900 cyc);
// B (L2-hot Wt) gets one. vmcnt(0) only at the last two steps.
// WAR: DMA at s targets A-buf (s+2)%3, read last at step s-1; those ds_reads are
//   register-consumed by MFMA issued before barrier s => complete. Same for B.
__global__ __launch_bounds__(NTH, 2)
void k_conv8(const _Float16* __restrict__ featb, const _Float16* __restrict__ wt,
             const char* __restrict__ zeros, float* __restrict__ out) {
  extern __shared__ char lds[];
  char* ldsB = lds + 98304;

  const int braw = blockIdx.x;
  const int b    = (braw & 7) * 54 + (braw >> 3);   // bijective XCD swizzle (432 = 8*54)
  const int p    = b & 1;                            // output-voxel parity
  const int tile = b >> 1;                           // 0..215

  const int tid = threadIdx.x;
  const int w   = tid >> 6;
  const int l   = tid & 63;

  // ---- staging geometry: thread stages rows rr and 128+rr; 4 lanes/row, 16B slots
  const int rr  = w * 16 + (l >> 2);                 // [0,128)
  const int swz = ((l & 3) ^ ((l >> 3) & 3)) * 16;   // slot XOR, key=((row&15)>>1)&3

  int xs[2], ys[2], zs[2];
#pragma unroll
  for (int q = 0; q < 2; ++q) {
    int e = tile * 256 + q * 128 + rr;
    int c = e / 24;
    int zi = e - c * 24;
    int x = c / 48;
    int y = c - x * 48;
    xs[q] = x; ys[q] = y; zs[q] = 2 * zi + ((x + y + p) & 1);
  }
  const char* wtc   = (const char*)wt;
  const char* featc = (const char*)featb;
  const int bro0 = rr * 512 + swz;                   // Wt row byte offsets
  const int bro1 = (128 + rr) * 512 + swz;

  // ---- fragment-read geometry ----
  const int wm = w >> 2, wn = w & 3;
  const int lr = l & 15, kg = l >> 4;
  const int rsw = (kg ^ ((lr >> 1) & 3)) * 16;       // read-side swizzle (involution)
  const int aRd = (wm * 128 + lr) * 64 + rsw;
  const int bRd = (wn * 64 + lr) * 64 + rsw;

  // ---- offset state: A tracks step s+2, B tracks step s+1 ----
  const char* asrc[2];
  auto setoffA = [&](int d27) {
    int dx = d27 / 9 - 1, dy = (d27 / 3) % 3 - 1, dz = d27 % 3 - 1;
#pragma unroll
    for (int q = 0; q < 2; ++q) {
      int ux = xs[q] + dx, uy = ys[q] + dy, uz = zs[q] + dz;
      bool v = (unsigned)ux < 48u && (unsigned)uy < 48u && (unsigned)uz < 48u;
      int idx = (ux * 48 + uy) * 24 + (uz >> 1);     // analytic even-lattice row id
      asrc[q] = (v ? (featc + idx * 512) : zeros) + swz;
    }
  };

  const int pb = p ? 0 : 1;                          // first offset with sum-parity p
  const char* wtileB = wtc + pb * 131072;
  setoffA(pb);

  // ---- prologue: B(0) then A(0), A(1) (queue order matters for vmcnt ledger) ----
  gload16(wtileB + bro0,      ldsB + 16384 + w * 1024);       // B0 ks0 hi? no: couts 0-127 ks0
  // (layout: Bbuf: ks0 couts0-127 @+0, couts128-255 @+8192; ks1 @+16384,+24576)
  // fix order below properly:
  ;
  {
    char* Bb = ldsB;                                  // buffer 0
    gload16(wtileB + bro0,      Bb + 0     + w * 1024);
    gload16(wtileB + bro1,      Bb + 8192  + w * 1024);
    gload16(wtileB + bro0 + 64, Bb + 16384 + w * 1024);
    gload16(wtileB + bro1 + 64, Bb + 24576 + w * 1024);
  }
  __builtin_amdgcn_sched_barrier(0);
  {
    char* Ab = lds;                                   // A step 0, buffer 0, kb=0
    gload16(asrc[0],      Ab + 0     + w * 1024);
    gload16(asrc[1],      Ab + 8192  + w * 1024);
    gload16(asrc[0] + 64, Ab + 16384 + w * 1024);
    gload16(asrc[1] + 64, Ab + 24576 + w * 1024);
  }
  __builtin_amdgcn_sched_barrier(0);
  {
    char* Ab = lds + 32768;                           // A step 1, buffer 1, kb=128
    gload16(asrc[0] + 128, Ab + 0     + w * 1024);
    gload16(asrc[1] + 128, Ab + 8192  + w * 1024);
    gload16(asrc[0] + 192, Ab + 16384 + w * 1024);
    gload16(asrc[1] + 192, Ab + 24576 + w * 1024);
  }

  f32x4 acc[8][4];
#pragma unroll
  for (int i = 0; i < 8; ++i)
#pragma unroll
    for (int j = 0; j < 4; ++j) acc[i][j] = (f32x4)0.0f;

  const int S = p ? 56 : 52;                         // (14 or 13 offsets) * 4 K-steps

  for (int s = 0; s < S; ++s) {
    // counted wait: B(s) landed (=> A(s), A(s+1) retired); A(s+2) stays in flight
    if (s + 2 < S) asm volatile("s_waitcnt vmcnt(4)" ::: "memory");
    else           asm volatile("s_waitcnt vmcnt(0)" ::: "memory");
    __builtin_amdgcn_s_barrier();
    __builtin_amdgcn_sched_barrier(0);

    // ---- issue B(s+1) into Bbuf[(s+1)&1] (FIRST: older in queue than A(s+2)) ----
    const int sB = s + 1;
    if (sB < S) {
      if ((sB & 3) == 0) wtileB = wtc + (pb + ((sB >> 2) << 1)) * 131072;
      const int kb = (sB & 3) * 128;
      char* Bb = ldsB + (sB & 1) * 32768;
      gload16(wtileB + bro0 + kb,      Bb + 0     + w * 1024);
      gload16(wtileB + bro1 + kb,      Bb + 8192  + w * 1024);
      gload16(wtileB + bro0 + kb + 64, Bb + 16384 + w * 1024);
      gload16(wtileB + bro1 + kb + 64, Bb + 24576 + w * 1024);
    }
    __builtin_amdgcn_sched_barrier(0);

    // ---- issue A(s+2) into Abuf[(s+2)%3] (two steps of flight time) ----
    const int sA = s + 2;
    if (sA < S) {
      if ((sA & 3) == 0) setoffA(pb + ((sA >> 2) << 1));
      const int kb = (sA & 3) * 128;
      int ia = sA - (sA / 3) * 3;                    // sA % 3
      char* Ab = lds + ia * 32768;
      gload16(asrc[0] + kb,      Ab + 0     + w * 1024);
      gload16(asrc[1] + kb,      Ab + 8192  + w * 1024);
      gload16(asrc[0] + kb + 64, Ab + 16384 + w * 1024);
      gload16(asrc[1] + kb + 64, Ab + 24576 + w * 1024);
    }
    __builtin_amdgcn_sched_barrier(0);

    // ---- 24 ds_reads from Abuf[s%3], Bbuf[s&1] (drain under MFMA via counted lgkm) ----
    const int ic = s - (s / 3) * 3;                  // s % 3
    const char* Ab = lds + ic * 32768;
    const char* Bb = ldsB + (s & 1) * 32768;

    half8 a0[8], a1[8], b0[4], b1[4];
#pragma unroll
    for (int nf = 0; nf < 4; ++nf) b0[nf] = *(const half8*)(Bb + bRd + nf * 1024);
#pragma unroll
    for (int mf = 0; mf < 8; ++mf) a0[mf] = *(const half8*)(Ab + aRd + mf * 1024);
#pragma unroll
    for (int nf = 0; nf < 4; ++nf) b1[nf] = *(const half8*)(Bb + 16384 + bRd + nf * 1024);
#pragma unroll
    for (int mf = 0; mf < 8; ++mf) a1[mf] = *(const half8*)(Ab + 16384 + aRd + mf * 1024);
    __builtin_amdgcn_sched_barrier(0);

    __builtin_amdgcn_s_setprio(1);
#pragma unroll
    for (int mf = 0; mf < 8; ++mf)
#pragma unroll
      for (int nf = 0; nf < 4; ++nf)
        acc[mf][nf] = __builtin_amdgcn_mfma_f32_16x16x32_f16(a0[mf], b0[nf], acc[mf][nf], 0, 0, 0);
#pragma unroll
    for (int mf = 0; mf < 8; ++mf)
#pragma unroll
      for (int nf = 0; nf < 4; ++nf)
        acc[mf][nf] = __builtin_amdgcn_mfma_f32_16x16x32_f16(a1[mf], b1[nf], acc[mf][nf], 0, 0, 0);
    __builtin_amdgcn_s_setprio(0);
  }

  // ---- epilogue: analytic output row (no LDS); C/D layout col=lane&15, row=(lane>>4)*4+i
#pragma unroll
  for (int mf = 0; mf < 8; ++mf) {
#pragma unroll
    for (int i = 0; i < 4; ++i) {
      int r = wm * 128 + mf * 16 + kg * 4 + i;
      int e = tile * 256 + r;
      int c = e / 24;
      int zi = e - c * 24;
      int x = c / 48;
      int y = c - x * 48;
      int o = c * 48 + 2 * zi + ((x + y + p) & 1);
      float* dst = out + (size_t)o * COUT + wn * 64 + lr;
#pragma unroll
      for (int nf = 0; nf < 4; ++nf) dst[nf * 16] = acc[mf][nf][i];
    }
  }
}

extern "C" void kernel_launch(void* const* d_in, const int* in_sizes, int n_in,
                              void* d_out, int out_size, void* d_ws, size_t ws_size,
                              hipStream_t stream) {
  const float* features = (const float*)d_in[0];
  const float* W = (const float*)d_in[3];
  float* out = (float*)d_out;

  char* ws = (char*)d_ws;
  _Float16* featb = (_Float16*)ws;                      // 28,311,552 B
  _Float16* Wt    = (_Float16*)(ws + 28311552);         //  3,538,944 B
  float*    zeros = (float*)(ws + 28311552 + 3538944);  //       512 B

  (void)hipFuncSetAttribute(reinterpret_cast<const void*>(k_conv8),
                            hipFuncAttributeMaxDynamicSharedMemorySize, 163840);

  {
    int n4 = NIN * CIN / 4;
    k_feat_cvt<<<(n4 + 255) / 256, 256, 0, stream>>>(features, featb, n4);
  }
  k_w_cvt<<<27 * 65536 / 256, 256, 0, stream>>>(W, Wt, zeros);

  k_conv8<<<NBLK, NTH, 163840, stream>>>(featb, Wt, (const char*)zeros, out);
}

// Round 12
// 214.683 us; speedup vs baseline: 1.0228x; 1.0228x over previous
//
#include <hip/hip_runtime.h>

#define NIN   55296
#define CIN   256
#define COUT  256
#define NTH   512
#define NBLK  432   // 2 parities * 216 tiles of 256 rows

typedef __attribute__((ext_vector_type(8))) _Float16 half8;
typedef __attribute__((ext_vector_type(4))) _Float16 half4;
typedef __attribute__((ext_vector_type(4))) float f32x4;

typedef const __attribute__((address_space(1))) void* gp_t;
typedef __attribute__((address_space(3))) void* lp_t;
__device__ __forceinline__ void gload16(const void* g, char* l) {
  __builtin_amdgcn_global_load_lds((gp_t)g, (lp_t)l, 16, 0, 0);
}

// ---------- pre-pass: features f32 -> f16 ----------
__global__ void k_feat_cvt(const float* __restrict__ f, _Float16* __restrict__ o, int n4) {
  int i = blockIdx.x * blockDim.x + threadIdx.x;
  if (i >= n4) return;
  f32x4 v = ((const f32x4*)f)[i];
  half4 r;
  r[0] = (_Float16)v[0]; r[1] = (_Float16)v[1];
  r[2] = (_Float16)v[2]; r[3] = (_Float16)v[3];
  ((half4*)o)[i] = r;
}

// ---------- pre-pass: W f32 [27][cin][cout] -> f16 transposed Wt [27][cout][cin]
__global__ void k_w_cvt(const float* __restrict__ W, _Float16* __restrict__ Wt,
                        float* __restrict__ zeros) {
  int i = blockIdx.x * blockDim.x + threadIdx.x;
  int d   = i >> 16;
  int rem = i & 65535;
  int n   = rem >> 8;
  int k   = rem & 255;
  Wt[i] = (_Float16)W[(d << 16) + (k << 8) + n];
  if (blockIdx.x == 0 && threadIdx.x < 128) zeros[threadIdx.x] = 0.0f;
}

// ---------- main: 8-wave 256x256 tile, BK=64, dbuf LDS, 1 barrier/step ----------
// r3 base + CHECKERBOARD WAVE STAGGER: even waves consume ksub0 then ksub1; odd
// waves ksub1 then ksub0. Breaks the bulk-synchronous pattern where all 8 waves
// issue 24 ds_reads simultaneously (LDS FIFO busy ~2300cy while MFMA idles, then
// MFMA ~2500cy while LDS idles). With stagger, at any instant ~half the waves
// feed LDS and half feed MFMA. Accumulation commutative; both halves staged
// before the barrier -> no hazard.
// LDS half d at d*65536: A_ks0 @0, A_ks1 @16384, B_ks0 @32768, B_ks1 @49152.
__global__ __launch_bounds__(NTH, 2)
void k_conv8(const _Float16* __restrict__ featb, const _Float16* __restrict__ wt,
             const char* __restrict__ zeros, float* __restrict__ out) {
  extern __shared__ char lds[];

  const int braw = blockIdx.x;
  const int b    = (braw & 7) * 54 + (braw >> 3);   // bijective XCD swizzle (432 = 8*54)
  const int p    = b & 1;                            // output-voxel parity
  const int tile = b >> 1;                           // 0..215

  const int tid = threadIdx.x;
  const int w   = tid >> 6;
  const int l   = tid & 63;

  // ---- staging geometry: thread stages rows rr, 128+rr; 4 lanes/row, 16B slots
  const int rr  = w * 16 + (l >> 2);                 // [0,128)
  const int swz = ((l & 3) ^ ((l >> 3) & 3)) * 16;   // slot XOR swizzle

  int xs[2], ys[2], zs[2];
#pragma unroll
  for (int q = 0; q < 2; ++q) {
    int e = tile * 256 + q * 128 + rr;
    int c = e / 24;
    int zi = e - c * 24;
    int x = c / 48;
    int y = c - x * 48;
    xs[q] = x; ys[q] = y; zs[q] = 2 * zi + ((x + y + p) & 1);
  }
  const char* wtc   = (const char*)wt;
  const char* featc = (const char*)featb;
  const int bro0 = rr * 512 + swz;                   // Wt row byte offsets
  const int bro1 = (128 + rr) * 512 + swz;

  // ---- fragment-read geometry ----
  const int wm = w >> 2, wn = w & 3;
  const int lr = l & 15, kg = l >> 4;
  const int rsw = (kg ^ ((lr >> 1) & 3)) * 16;       // read-side swizzle (involution)
  const int aRd = (wm * 128 + lr) * 64 + rsw;
  const int bRd = (wn * 64 + lr) * 64 + rsw;

  // ---- checkerboard stagger: first-half k-sub offset per wave parity ----
  const int h1 = (w & 1) << 14;                      // 0 or 16384
  const int h2 = h1 ^ 16384;

  // ---- prefetch-side offset state ----
  const char* asrc[2];
  const char* wtile;
  auto setoff = [&](int d27) {
    int dx = d27 / 9 - 1, dy = (d27 / 3) % 3 - 1, dz = d27 % 3 - 1;
#pragma unroll
    for (int q = 0; q < 2; ++q) {
      int ux = xs[q] + dx, uy = ys[q] + dy, uz = zs[q] + dz;
      bool v = (unsigned)ux < 48u && (unsigned)uy < 48u && (unsigned)uz < 48u;
      int idx = (ux * 48 + uy) * 24 + (uz >> 1);     // analytic even-lattice row id
      asrc[q] = (v ? (featc + idx * 512) : zeros) + swz;
    }
    wtile = wtc + d27 * 131072;
  };

  int pn = p ? 0 : 1;                                // offsets with sum-parity p, step 2
  setoff(pn);

  // ---- prologue: stage K-step 0 into buffer 0 (8 gloads, both k-halves) ----
  gload16(asrc[0],            lds + 0     + w * 1024);
  gload16(asrc[1],            lds + 8192  + w * 1024);
  gload16(asrc[0] + 64,       lds + 16384 + w * 1024);
  gload16(asrc[1] + 64,       lds + 24576 + w * 1024);
  gload16(wtile + bro0,       lds + 32768 + w * 1024);
  gload16(wtile + bro1,       lds + 40960 + w * 1024);
  gload16(wtile + bro0 + 64,  lds + 49152 + w * 1024);
  gload16(wtile + bro1 + 64,  lds + 57344 + w * 1024);

  f32x4 acc[8][4];
#pragma unroll
  for (int i = 0; i < 8; ++i)
#pragma unroll
    for (int j = 0; j < 4; ++j) acc[i][j] = (f32x4)0.0f;

  const int S = p ? 56 : 52;                         // (14 or 13 offsets) * 4 K-steps

  for (int s = 0; s < S; ++s) {
    __syncthreads();   // vmcnt(0): DMA into buf d landed; d^1 readers done

    const char* Ab = lds + (s & 1) * 65536;
    const char* Bb = Ab + 32768;

    // ---- issue next-step staging into buf d^1 ----
    const int sn = s + 1;
    if (sn < S) {
      if ((sn & 3) == 0) { pn += 2; setoff(pn); }
      char* Nb = lds + (sn & 1) * 65536;
      const int kb = (sn & 3) * 128;
      gload16(asrc[0] + kb,            Nb + 0     + w * 1024);
      gload16(asrc[1] + kb,            Nb + 8192  + w * 1024);
      gload16(asrc[0] + kb + 64,       Nb + 16384 + w * 1024);
      gload16(asrc[1] + kb + 64,       Nb + 24576 + w * 1024);
      gload16(wtile + bro0 + kb,       Nb + 32768 + w * 1024);
      gload16(wtile + bro1 + kb,       Nb + 40960 + w * 1024);
      gload16(wtile + bro0 + kb + 64,  Nb + 49152 + w * 1024);
      gload16(wtile + bro1 + kb + 64,  Nb + 57344 + w * 1024);
    }
    __builtin_amdgcn_sched_barrier(0);

    half8 a0[8], a1[8], b0[4], b1[4];

    // ---- sub-phase 1: this wave's first k-half (h1) ----
#pragma unroll
    for (int nf = 0; nf < 4; ++nf) b0[nf] = *(const half8*)(Bb + h1 + bRd + nf * 1024);
#pragma unroll
    for (int mf = 0; mf < 8; ++mf) a0[mf] = *(const half8*)(Ab + h1 + aRd + mf * 1024);
    __builtin_amdgcn_sched_barrier(0);

    __builtin_amdgcn_s_setprio(1);
#pragma unroll
    for (int mf = 0; mf < 8; ++mf)
#pragma unroll
      for (int nf = 0; nf < 4; ++nf)
        acc[mf][nf] = __builtin_amdgcn_mfma_f32_16x16x32_f16(a0[mf], b0[nf], acc[mf][nf], 0, 0, 0);
    __builtin_amdgcn_s_setprio(0);
    __builtin_amdgcn_sched_barrier(0);

    // ---- sub-phase 2: the other k-half (h2) ----
#pragma unroll
    for (int nf = 0; nf < 4; ++nf) b1[nf] = *(const half8*)(Bb + h2 + bRd + nf * 1024);
#pragma unroll
    for (int mf = 0; mf < 8; ++mf) a1[mf] = *(const half8*)(Ab + h2 + aRd + mf * 1024);
    __builtin_amdgcn_sched_barrier(0);

    __builtin_amdgcn_s_setprio(1);
#pragma unroll
    for (int mf = 0; mf < 8; ++mf)
#pragma unroll
      for (int nf = 0; nf < 4; ++nf)
        acc[mf][nf] = __builtin_amdgcn_mfma_f32_16x16x32_f16(a1[mf], b1[nf], acc[mf][nf], 0, 0, 0);
    __builtin_amdgcn_s_setprio(0);
  }

  // ---- epilogue: analytic output row; C/D layout col=lane&15, row=(lane>>4)*4+i
#pragma unroll
  for (int mf = 0; mf < 8; ++mf) {
#pragma unroll
    for (int i = 0; i < 4; ++i) {
      int r = wm * 128 + mf * 16 + kg * 4 + i;
      int e = tile * 256 + r;
      int c = e / 24;
      int zi = e - c * 24;
      int x = c / 48;
      int y = c - x * 48;
      int o = c * 48 + 2 * zi + ((x + y + p) & 1);
      float* dst = out + (size_t)o * COUT + wn * 64 + lr;
#pragma unroll
      for (int nf = 0; nf < 4; ++nf) dst[nf * 16] = acc[mf][nf][i];
    }
  }
}

extern "C" void kernel_launch(void* const* d_in, const int* in_sizes, int n_in,
                              void* d_out, int out_size, void* d_ws, size_t ws_size,
                              hipStream_t stream) {
  const float* features = (const float*)d_in[0];
  const float* W = (const float*)d_in[3];
  float* out = (float*)d_out;

  char* ws = (char*)d_ws;
  _Float16* featb = (_Float16*)ws;                      // 28,311,552 B
  _Float16* Wt    = (_Float16*)(ws + 28311552);         //  3,538,944 B
  float*    zeros = (float*)(ws + 28311552 + 3538944);  //       512 B

  (void)hipFuncSetAttribute(reinterpret_cast<const void*>(k_conv8),
                            hipFuncAttributeMaxDynamicSharedMemorySize, 131072);

  {
    int n4 = NIN * CIN / 4;
    k_feat_cvt<<<(n4 + 255) / 256, 256, 0, stream>>>(features, featb, n4);
  }
  k_w_cvt<<<27 * 65536 / 256, 256, 0, stream>>>(W, Wt, zeros);

  k_conv8<<<NBLK, NTH, 131072, stream>>>(featb, Wt, (const char*)zeros, out);
}

// Round 13
// 209.314 us; speedup vs baseline: 1.0491x; 1.0256x over previous
//
#include <hip/hip_runtime.h>

#define NIN   55296
#define CIN   256
#define COUT  256
#define NTH   512
#define NBLK  432   // 216 p=1 tiles first (14 offsets), then 216 p=0 tiles (13 offsets)

typedef __attribute__((ext_vector_type(8))) _Float16 half8;
typedef __attribute__((ext_vector_type(4))) _Float16 half4;
typedef __attribute__((ext_vector_type(4))) float f32x4;

typedef const __attribute__((address_space(1))) void* gp_t;
typedef __attribute__((address_space(3))) void* lp_t;
__device__ __forceinline__ void gload16(const void* g, char* l) {
  __builtin_amdgcn_global_load_lds((gp_t)g, (lp_t)l, 16, 0, 0);
}

// ---------- merged pre-pass: features f32->f16 (blocks 0..13823),
// ---------- W f32 [27][cin][cout] -> f16 Wt [27][cout][cin] (blocks 13824..20735),
// ---------- + 512B zero page (first W block).
__global__ void k_pre(const float* __restrict__ f, _Float16* __restrict__ o,
                      const float* __restrict__ W, _Float16* __restrict__ Wt,
                      float* __restrict__ zeros) {
  int bid = blockIdx.x;
  if (bid < 13824) {
    int i = bid * 256 + threadIdx.x;              // < 3,538,944 = NIN*CIN/4
    f32x4 v = ((const f32x4*)f)[i];
    half4 r;
    r[0] = (_Float16)v[0]; r[1] = (_Float16)v[1];
    r[2] = (_Float16)v[2]; r[3] = (_Float16)v[3];
    ((half4*)o)[i] = r;
  } else {
    int i = (bid - 13824) * 256 + threadIdx.x;    // < 1,769,472 = 27*65536
    int d   = i >> 16;
    int rem = i & 65535;
    int n   = rem >> 8;    // cout
    int k   = rem & 255;   // cin
    Wt[i] = (_Float16)W[(d << 16) + (k << 8) + n];
    if (bid == 13824 && threadIdx.x < 128) zeros[threadIdx.x] = 0.0f;
  }
}

// ---------- main: 8-wave 256x256 tile, BK=64, dbuf LDS, 1 barrier/step (r3 body) ----------
// Grid order: p=1 (14-offset, LONG) blocks 0..215 dispatch first; p=0 (13-offset,
// SHORT) blocks 216..431 fill the 176-block tail round => tail is ~7% cheaper.
// XCD swizzle bijective within each parity group (216 = 8*27).
// LDS half d at d*65536: A_ks0 @0, A_ks1 @16384, B_ks0 @32768, B_ks1 @49152. orow @131072.
__global__ __launch_bounds__(NTH, 2)
void k_conv8(const _Float16* __restrict__ featb, const _Float16* __restrict__ wt,
             const char* __restrict__ zeros, float* __restrict__ out) {
  extern __shared__ char lds[];
  int* orow = (int*)(lds + 131072);

  const int braw = blockIdx.x;
  const int p    = (braw < 216) ? 1 : 0;             // long blocks first
  const int g    = braw - (p ? 0 : 216);             // [0,216)
  const int tile = (g & 7) * 27 + (g >> 3);          // bijective XCD swizzle (216 = 8*27)

  const int tid = threadIdx.x;
  const int w   = tid >> 6;
  const int l   = tid & 63;

  // ---- staging geometry: thread stages rows rr, 128+rr; 4 lanes/row, 16B slots
  const int rr  = w * 16 + (l >> 2);                 // [0,128)
  const int swz = ((l & 3) ^ ((l >> 3) & 3)) * 16;   // slot XOR swizzle

  int xs[2], ys[2], zs[2];
#pragma unroll
  for (int q = 0; q < 2; ++q) {
    int e = tile * 256 + q * 128 + rr;
    int c = e / 24;
    int zi = e - c * 24;
    int x = c / 48;
    int y = c - x * 48;
    xs[q] = x; ys[q] = y; zs[q] = 2 * zi + ((x + y + p) & 1);
  }
  const char* wtc   = (const char*)wt;
  const char* featc = (const char*)featb;
  const int bro0 = rr * 512 + swz;                   // Wt row byte offsets
  const int bro1 = (128 + rr) * 512 + swz;

  // ---- fragment-read geometry ----
  const int wm = w >> 2, wn = w & 3;
  const int lr = l & 15, kg = l >> 4;
  const int rsw = (kg ^ ((lr >> 1) & 3)) * 16;       // read-side swizzle (involution)
  const int aRd = (wm * 128 + lr) * 64 + rsw;
  const int bRd = (wn * 64 + lr) * 64 + rsw;

  // ---- orow table (visible after first __syncthreads) ----
  if (tid < 256) {
    int e = tile * 256 + tid;
    int c = e / 24;
    int zi = e - c * 24;
    int x = c / 48;
    int y = c - x * 48;
    int z = 2 * zi + ((x + y + p) & 1);
    orow[tid] = (x * 48 + y) * 48 + z;
  }

  // ---- prefetch-side offset state ----
  const char* asrc[2];
  const char* wtile;
  auto setoff = [&](int d27) {
    int dx = d27 / 9 - 1, dy = (d27 / 3) % 3 - 1, dz = d27 % 3 - 1;
#pragma unroll
    for (int q = 0; q < 2; ++q) {
      int ux = xs[q] + dx, uy = ys[q] + dy, uz = zs[q] + dz;
      bool v = (unsigned)ux < 48u && (unsigned)uy < 48u && (unsigned)uz < 48u;
      int idx = (ux * 48 + uy) * 24 + (uz >> 1);     // analytic even-lattice row id
      asrc[q] = (v ? (featc + idx * 512) : zeros) + swz;
    }
    wtile = wtc + d27 * 131072;
  };

  int pn = p ? 0 : 1;                                // offsets with sum-parity p, step 2
  setoff(pn);

  // ---- prologue: stage K-step 0 into buffer 0 (8 gloads) ----
  gload16(asrc[0],            lds + 0     + w * 1024);
  gload16(asrc[1],            lds + 8192  + w * 1024);
  gload16(asrc[0] + 64,       lds + 16384 + w * 1024);
  gload16(asrc[1] + 64,       lds + 24576 + w * 1024);
  gload16(wtile + bro0,       lds + 32768 + w * 1024);
  gload16(wtile + bro1,       lds + 40960 + w * 1024);
  gload16(wtile + bro0 + 64,  lds + 49152 + w * 1024);
  gload16(wtile + bro1 + 64,  lds + 57344 + w * 1024);

  f32x4 acc[8][4];
#pragma unroll
  for (int i = 0; i < 8; ++i)
#pragma unroll
    for (int j = 0; j < 4; ++j) acc[i][j] = (f32x4)0.0f;

  const int S = p ? 56 : 52;                         // (14 or 13 offsets) * 4 K-steps

  for (int s = 0; s < S; ++s) {
    __syncthreads();   // vmcnt(0): DMA into buf d landed; d^1 readers done

    const char* Ab = lds + (s & 1) * 65536;

    // ---- frag ds_reads from buf d (drain under MFMA via compiler's counted lgkm) ----
    half8 a0[8], a1[8], b0[4], b1[4];
#pragma unroll
    for (int nf = 0; nf < 4; ++nf) b0[nf] = *(const half8*)(Ab + 32768 + bRd + nf * 1024);
#pragma unroll
    for (int mf = 0; mf < 8; ++mf) a0[mf] = *(const half8*)(Ab + aRd + mf * 1024);
#pragma unroll
    for (int nf = 0; nf < 4; ++nf) b1[nf] = *(const half8*)(Ab + 49152 + bRd + nf * 1024);
#pragma unroll
    for (int mf = 0; mf < 8; ++mf) a1[mf] = *(const half8*)(Ab + 16384 + aRd + mf * 1024);

    // ---- issue next-step staging into buf d^1 (consumed after NEXT barrier) ----
    const int sn = s + 1;
    if (sn < S) {
      if ((sn & 3) == 0) { pn += 2; setoff(pn); }
      char* Nb = lds + (sn & 1) * 65536;
      const int kb = (sn & 3) * 128;
      gload16(asrc[0] + kb,            Nb + 0     + w * 1024);
      gload16(asrc[1] + kb,            Nb + 8192  + w * 1024);
      gload16(asrc[0] + kb + 64,       Nb + 16384 + w * 1024);
      gload16(asrc[1] + kb + 64,       Nb + 24576 + w * 1024);
      gload16(wtile + bro0 + kb,       Nb + 32768 + w * 1024);
      gload16(wtile + bro1 + kb,       Nb + 40960 + w * 1024);
      gload16(wtile + bro0 + kb + 64,  Nb + 49152 + w * 1024);
      gload16(wtile + bro1 + kb + 64,  Nb + 57344 + w * 1024);
    }
    __builtin_amdgcn_sched_barrier(0);   // keep load issues above the MFMA block

    __builtin_amdgcn_s_setprio(1);
#pragma unroll
    for (int mf = 0; mf < 8; ++mf)
#pragma unroll
      for (int nf = 0; nf < 4; ++nf)
        acc[mf][nf] = __builtin_amdgcn_mfma_f32_16x16x32_f16(a0[mf], b0[nf], acc[mf][nf], 0, 0, 0);
#pragma unroll
    for (int mf = 0; mf < 8; ++mf)
#pragma unroll
      for (int nf = 0; nf < 4; ++nf)
        acc[mf][nf] = __builtin_amdgcn_mfma_f32_16x16x32_f16(a1[mf], b1[nf], acc[mf][nf], 0, 0, 0);
    __builtin_amdgcn_s_setprio(0);
  }

  // ---- epilogue: C/D layout col=lane&15, row=(lane>>4)*4+i ----
#pragma unroll
  for (int mf = 0; mf < 8; ++mf) {
#pragma unroll
    for (int i = 0; i < 4; ++i) {
      int r = wm * 128 + mf * 16 + kg * 4 + i;
      int o = orow[r];
      float* dst = out + (size_t)o * COUT + wn * 64 + lr;
#pragma unroll
      for (int nf = 0; nf < 4; ++nf) dst[nf * 16] = acc[mf][nf][i];
    }
  }
}

extern "C" void kernel_launch(void* const* d_in, const int* in_sizes, int n_in,
                              void* d_out, int out_size, void* d_ws, size_t ws_size,
                              hipStream_t stream) {
  const float* features = (const float*)d_in[0];
  const float* W = (const float*)d_in[3];
  float* out = (float*)d_out;

  char* ws = (char*)d_ws;
  _Float16* featb = (_Float16*)ws;                      // 28,311,552 B
  _Float16* Wt    = (_Float16*)(ws + 28311552);         //  3,538,944 B
  float*    zeros = (float*)(ws + 28311552 + 3538944);  //       512 B

  (void)hipFuncSetAttribute(reinterpret_cast<const void*>(k_conv8),
                            hipFuncAttributeMaxDynamicSharedMemorySize, 132096);

  // merged pre-pass: 13824 feature-cvt blocks + 6912 W-transpose blocks
  k_pre<<<20736, 256, 0, stream>>>(features, featb, W, Wt, zeros);

  k_conv8<<<NBLK, NTH, 132096, stream>>>(featb, Wt, (const char*)zeros, out);
}